// Round 7
// baseline (430.647 us; speedup 1.0000x reference)
//
#include <hip/hip_runtime.h>
#include <math.h>

#define N_NODES 20000
#define N_EDG   320000
#define NB      64
#define EMBD    32
#define HIDD    128
#define NHEAD   4
#define OUTC    512      // H * HID
#define LN_EPS  1e-5f
#define NEG_SLOPE 0.2f

typedef unsigned int u32;
typedef unsigned short u16;
typedef __attribute__((ext_vector_type(8))) short s16x8;
typedef __attribute__((ext_vector_type(4))) float f32x4;

__device__ __forceinline__ float lrelu(float x){ return x >= 0.f ? x : NEG_SLOPE * x; }

__device__ __forceinline__ float2 bf2f(u32 p){
  float2 r;
  r.x = __uint_as_float(p << 16);
  r.y = __uint_as_float(p & 0xffff0000u);
  return r;
}
__device__ __forceinline__ u16 f2bf(float a){
  u32 ua = __float_as_uint(a);
  return (u16)((ua + 0x7fffu + ((ua >> 16) & 1u)) >> 16);
}
__device__ __forceinline__ u32 pack2bf(float a, float b){
  return (u32)f2bf(a) | ((u32)f2bf(b) << 16);
}

// ---------------- CSR construction ----------------
__global__ void k_deg(const int* __restrict__ dst, int* __restrict__ deg){
  int e = blockIdx.x * blockDim.x + threadIdx.x;
  if (e < N_EDG) atomicAdd(&deg[dst[e]], 1);
}

__global__ __launch_bounds__(1024) void k_scan(const int* __restrict__ deg,
                                               int* __restrict__ rowptr,
                                               int* __restrict__ cursor){
  __shared__ int sums[1024];
  const int CH = (N_NODES + 1023) / 1024;   // 20
  int t = threadIdx.x;
  int start = t * CH;
  int end = min(start + CH, N_NODES);
  int s = 0;
  for (int i = start; i < end; ++i) s += deg[i];
  sums[t] = s;
  __syncthreads();
  for (int off = 1; off < 1024; off <<= 1){
    int v = (t >= off) ? sums[t - off] : 0;
    __syncthreads();
    sums[t] += v;
    __syncthreads();
  }
  int run = (t > 0) ? sums[t - 1] : 0;
  for (int i = start; i < end; ++i){
    rowptr[i] = run; cursor[i] = run; run += deg[i];
  }
  if (t == 0) rowptr[N_NODES] = sums[1023];
}

__global__ void k_scatter(const int* __restrict__ src, const int* __restrict__ dst,
                          int* __restrict__ cursor,
                          int* __restrict__ csr_src, int* __restrict__ csr_dst,
                          int* __restrict__ epos){
  int e = blockIdx.x * blockDim.x + threadIdx.x;
  if (e < N_EDG){
    int d = dst[e];
    int p = atomicAdd(&cursor[d], 1);
    csr_src[p] = src[e];
    csr_dst[p] = d;
    epos[e] = p;
  }
}

// graph boundaries from sorted batch
__global__ void k_bounds(const int* __restrict__ batch, int* __restrict__ bnd){
  int n = blockIdx.x * blockDim.x + threadIdx.x;
  if (n >= N_NODES) return;
  int b = batch[n];
  int bp = (n == 0) ? -1 : batch[n - 1];
  for (int g = bp + 1; g <= b; ++g) bnd[g] = n;
  if (n == N_NODES - 1){
    for (int g = b + 1; g <= NB; ++g) bnd[g] = N_NODES;
  }
}

// ---------------- attention-vector folding ----------------
// vfold[L]: [0,512) v_src[k*4+h], [512,1024) v_dst, [1024,1152) v_e
__global__ void k_fold(const float* __restrict__ W0, const float* __restrict__ W1,
                       const float* __restrict__ W2, const float* __restrict__ lin_edge,
                       const float* __restrict__ att_src, const float* __restrict__ att_dst,
                       const float* __restrict__ att_edge, float* __restrict__ vfold){
  int L = blockIdx.y;
  int in_dim = L ? HIDD : EMBD;
  const float* W  = (L == 0) ? W0 : ((L == 1) ? W1 : W2);
  const float* We = lin_edge + (size_t)L * EMBD * OUTC;
  const float* as = att_src + L * 512;
  const float* ad = att_dst + L * 512;
  const float* ae = att_edge + L * 512;
  float* vf = vfold + L * 1152;
  int j = blockIdx.x * blockDim.x + threadIdx.x;
  int nsrc = in_dim * NHEAD;
  if (j < nsrc){
    int k = j >> 2, h = j & 3;
    float s = 0.f;
    for (int c = 0; c < HIDD; ++c) s += W[k * OUTC + h * HIDD + c] * as[h * HIDD + c];
    vf[k * 4 + h] = s;
  } else if (j < 2 * nsrc){
    int jj = j - nsrc; int k = jj >> 2, h = jj & 3;
    float s = 0.f;
    for (int c = 0; c < HIDD; ++c) s += W[k * OUTC + h * HIDD + c] * ad[h * HIDD + c];
    vf[512 + k * 4 + h] = s;
  } else if (j < 2 * nsrc + EMBD * NHEAD){
    int jj = j - 2 * nsrc; int k = jj >> 2, h = jj & 3;
    float s = 0.f;
    for (int c = 0; c < HIDD; ++c) s += We[k * OUTC + h * HIDD + c] * ae[h * HIDD + c];
    vf[1024 + k * 4 + h] = s;
  }
}

// ---------------- dtype prep ----------------
__global__ void k_cvt_x(const float* __restrict__ x, u16* __restrict__ xb){
  int i = blockIdx.x * blockDim.x + threadIdx.x;
  if (i < N_NODES * EMBD) xb[i] = f2bf(x[i]);
}
__global__ void k_cvt_w(const float* __restrict__ W0, const float* __restrict__ W1,
                        const float* __restrict__ W2,
                        u16* __restrict__ t0, u16* __restrict__ t1, u16* __restrict__ t2){
  int L = blockIdx.y;
  int K = L ? HIDD : EMBD;
  const float* W = (L == 0) ? W0 : ((L == 1) ? W1 : W2);
  u16* T = (L == 0) ? t0 : ((L == 1) ? t1 : t2);
  int j = blockIdx.x * blockDim.x + threadIdx.x;
  if (j < OUTC * K){
    int n = j / K, k = j % K;
    T[j] = f2bf(W[(size_t)k * OUTC + n]);
  }
}

// ---------------- one-time edge projection: ea -> ev per layer, CSR order ----------------
__global__ __launch_bounds__(256) void k_edgeproj(const float* __restrict__ ea,
                                                  const int* __restrict__ epos,
                                                  const float* __restrict__ vfold,
                                                  float4* __restrict__ eaPc){
  __shared__ float vs[384];
  for (int i = threadIdx.x; i < 384; i += 256)
    vs[i] = vfold[(i >> 7) * 1152 + 1024 + (i & 127)];
  __syncthreads();
  int e = blockIdx.x * blockDim.x + threadIdx.x;
  if (e >= N_EDG) return;
  float4 a[8];
  const float4* er = (const float4*)(ea + (size_t)e * EMBD);
  #pragma unroll
  for (int i = 0; i < 8; ++i) a[i] = er[i];
  int p = epos[e];
  #pragma unroll
  for (int L = 0; L < 3; ++L){
    const float* v = vs + L * 128;
    float ev[4] = {0,0,0,0};
    #pragma unroll
    for (int q = 0; q < 8; ++q){
      #pragma unroll
      for (int h = 0; h < 4; ++h){
        ev[h] += a[q].x * v[(q*4+0)*4+h] + a[q].y * v[(q*4+1)*4+h]
               + a[q].z * v[(q*4+2)*4+h] + a[q].w * v[(q*4+3)*4+h];
      }
    }
    eaPc[(size_t)L * N_EDG + p] = make_float4(ev[0], ev[1], ev[2], ev[3]);
  }
}

__device__ __forceinline__ float wsum(float v){
  #pragma unroll
  for (int off = 32; off > 0; off >>= 1) v += __shfl_xor(v, off);
  return v;
}
__device__ __forceinline__ float wmax(float v){
  #pragma unroll
  for (int off = 32; off > 0; off >>= 1) v = fmaxf(v, __shfl_xor(v, off));
  return v;
}

__global__ __launch_bounds__(256) void k_projsum(const float4* __restrict__ eaPc,
                                                 const int* __restrict__ rowptr,
                                                 float4* __restrict__ proj){
  int wid = threadIdx.x >> 6, lane = threadIdx.x & 63;
  int n = blockIdx.x * 4 + wid;
  if (n >= N_NODES) return;
  int rs = rowptr[n], re = rowptr[n + 1];
  #pragma unroll
  for (int L = 0; L < 3; ++L){
    float a0 = 0.f, a1 = 0.f, a2 = 0.f, a3 = 0.f;
    for (int p = rs + lane; p < re; p += 64){
      float4 v = eaPc[(size_t)L * N_EDG + p];
      a0 += v.x; a1 += v.y; a2 += v.z; a3 += v.w;
    }
    a0 = wsum(a0); a1 = wsum(a1); a2 = wsum(a2); a3 = wsum(a3);
    if (lane == 0) proj[(size_t)L * N_NODES + n] = make_float4(a0, a1, a2, a3);
  }
}

// ---------------- MFMA bf16 GEMM ----------------
template<int K>
__global__ __launch_bounds__(256) void k_gemm(const u16* __restrict__ Xb,
                                              const u16* __restrict__ Wt,
                                              u16* __restrict__ Hb,
                                              int M){
  const int CH = K + 8;
  __shared__ u16 ldsA[64 * CH];
  __shared__ u16 ldsB[128 * CH];
  int bm = blockIdx.y * 64, bn = blockIdx.x * 128;
  int t = threadIdx.x;
  for (int f = t; f < 64 * (K / 8); f += 256){
    int row = f / (K / 8), c8 = f % (K / 8);
    int gm = bm + row;
    uint4 v = make_uint4(0, 0, 0, 0);
    if (gm < M) v = *(const uint4*)(Xb + (size_t)gm * K + c8 * 8);
    *(uint4*)&ldsA[row * CH + c8 * 8] = v;
  }
  for (int f = t; f < 128 * (K / 8); f += 256){
    int row = f / (K / 8), c8 = f % (K / 8);
    *(uint4*)&ldsB[row * CH + c8 * 8] = *(const uint4*)(Wt + (size_t)(bn + row) * K + c8 * 8);
  }
  __syncthreads();

  int w = t >> 6, lane = t & 63;
  int r = lane & 15, g = lane >> 4;
  f32x4 acc[8];
  #pragma unroll
  for (int i = 0; i < 8; ++i) acc[i] = (f32x4){0.f, 0.f, 0.f, 0.f};
  const u16* pa = &ldsA[(w * 16 + r) * CH + g * 8];
  #pragma unroll
  for (int k0 = 0; k0 < K; k0 += 32){
    s16x8 a = *(const s16x8*)(pa + k0);
    #pragma unroll
    for (int nf = 0; nf < 8; ++nf){
      s16x8 b = *(const s16x8*)(&ldsB[(nf * 16 + r) * CH + k0 + g * 8]);
      acc[nf] = __builtin_amdgcn_mfma_f32_16x16x32_bf16(a, b, acc[nf], 0, 0, 0);
    }
  }
  #pragma unroll
  for (int nf = 0; nf < 8; ++nf){
    #pragma unroll
    for (int i = 0; i < 4; ++i){
      int gm = bm + w * 16 + g * 4 + i;
      if (gm < M) Hb[(size_t)gm * OUTC + bn + nf * 16 + r] = f2bf(acc[nf][i]);
    }
  }
}

// ---------------- per-node logits: s_src, s_dst, self-loop logit ----------------
__global__ __launch_bounds__(256) void k_nodelin(const float* __restrict__ X,
                                                 const float* __restrict__ vfold,
                                                 const float4* __restrict__ projL,
                                                 const int* __restrict__ deg,
                                                 float* __restrict__ s_src, float* __restrict__ s_dst,
                                                 float* __restrict__ al_loop, int in_dim){
  __shared__ float vs[1024];
  for (int i = threadIdx.x; i < 1024; i += 256) vs[i] = vfold[i];
  __syncthreads();
  int n = blockIdx.x * blockDim.x + threadIdx.x;
  if (n >= N_NODES) return;
  float a[4] = {0,0,0,0}, d[4] = {0,0,0,0};
  const float* xr = X + (size_t)n * in_dim;
  for (int k4 = 0; k4 < in_dim; k4 += 4){
    float4 xv = *(const float4*)(xr + k4);
    #pragma unroll
    for (int h = 0; h < 4; ++h){
      a[h] += xv.x * vs[(k4+0)*4+h] + xv.y * vs[(k4+1)*4+h]
            + xv.z * vs[(k4+2)*4+h] + xv.w * vs[(k4+3)*4+h];
      d[h] += xv.x * vs[512+(k4+0)*4+h] + xv.y * vs[512+(k4+1)*4+h]
            + xv.z * vs[512+(k4+2)*4+h] + xv.w * vs[512+(k4+3)*4+h];
    }
  }
  float4 pj = projL[n];
  float invd = 1.f / fmaxf((float)deg[n], 1.f);
  ((float4*)s_src)[n] = make_float4(a[0], a[1], a[2], a[3]);
  ((float4*)s_dst)[n] = make_float4(d[0], d[1], d[2], d[3]);
  float4 ll;
  ll.x = lrelu(a[0]+d[0]+pj.x*invd); ll.y = lrelu(a[1]+d[1]+pj.y*invd);
  ll.z = lrelu(a[2]+d[2]+pj.z*invd); ll.w = lrelu(a[3]+d[3]+pj.w*invd);
  ((float4*)al_loop)[n] = ll;
}

// ---------------- per-edge logit (CSR position indexed, all streams coalesced) ----------------
__global__ __launch_bounds__(256) void k_edgepart(const float4* __restrict__ eaPcL,
                                                  const int* __restrict__ csr_src,
                                                  const int* __restrict__ csr_dst,
                                                  const float4* __restrict__ s_src4,
                                                  const float4* __restrict__ s_dst4,
                                                  float4* __restrict__ alpc){
  int p = blockIdx.x * blockDim.x + threadIdx.x;
  if (p >= N_EDG) return;
  float4 ev = eaPcL[p];
  float4 ss = s_src4[csr_src[p]];
  float4 dd = s_dst4[csr_dst[p]];
  float4 o;
  o.x = lrelu(ss.x + dd.x + ev.x);
  o.y = lrelu(ss.y + dd.y + ev.y);
  o.z = lrelu(ss.z + dd.z + ev.z);
  o.w = lrelu(ss.w + dd.w + ev.w);
  alpc[p] = o;
}

// ---------------- wave-per-node aggregation: 2-pass softmax, shuffle-free weight loop ----------------
__global__ __launch_bounds__(256) void k_aggr(const uint4* __restrict__ Hb4,
                                              const float4* __restrict__ alpc,
                                              const float4* __restrict__ al_loop,
                                              const int* __restrict__ rowptr,
                                              const int* __restrict__ csr_src,
                                              const float* __restrict__ bias,
                                              const float* __restrict__ lng,
                                              const float* __restrict__ lnb,
                                              float* __restrict__ Xout,
                                              u16* __restrict__ XoutBf){
  int wid  = threadIdx.x >> 6;
  int lane = threadIdx.x & 63;
  int n = blockIdx.x * 4 + wid;
  if (n >= N_NODES) return;
  int h = lane >> 4;
  int rs = rowptr[n], re = rowptr[n + 1];

  float4 ll = al_loop[n];
  uint4 hv = Hb4[(size_t)n * 64 + lane];    // own row (prefetch)

  // ---- pass A: per-head max over edge logits (strided, lane-parallel) ----
  float m0 = ll.x, m1 = ll.y, m2 = ll.z, m3 = ll.w;
  for (int p = rs + lane; p < re; p += 64){
    float4 v = alpc[p];
    m0 = fmaxf(m0, v.x); m1 = fmaxf(m1, v.y);
    m2 = fmaxf(m2, v.z); m3 = fmaxf(m3, v.w);
  }
  m0 = wmax(m0); m1 = wmax(m1); m2 = wmax(m2); m3 = wmax(m3);
  float mh  = (h == 0) ? m0 : ((h == 1) ? m1 : ((h == 2) ? m2 : m3));
  float llh = (h == 0) ? ll.x : ((h == 1) ? ll.y : ((h == 2) ? ll.z : ll.w));

  // ---- pass B: uniform-broadcast loads, unnormalized accumulate, zero shuffles ----
  float s = __expf(llh - mh);               // self-loop weight
  float acc[8];
  { float2 p0 = bf2f(hv.x), p1 = bf2f(hv.y), p2 = bf2f(hv.z), p3 = bf2f(hv.w);
    acc[0]=s*p0.x; acc[1]=s*p0.y; acc[2]=s*p1.x; acc[3]=s*p1.y;
    acc[4]=s*p2.x; acc[5]=s*p2.y; acc[6]=s*p3.x; acc[7]=s*p3.y; }

  #pragma unroll 4
  for (int j = rs; j < re; ++j){
    float4 v = alpc[j];                     // uniform across wave -> broadcast
    int   sj = csr_src[j];                  // uniform
    float vh = (h == 0) ? v.x : ((h == 1) ? v.y : ((h == 2) ? v.z : v.w));
    float w = __expf(vh - mh);
    s += w;
    uint4 hb = Hb4[(size_t)sj * 64 + lane]; // coalesced row gather
    float2 p0 = bf2f(hb.x), p1 = bf2f(hb.y), p2 = bf2f(hb.z), p3 = bf2f(hb.w);
    acc[0] = fmaf(w, p0.x, acc[0]); acc[1] = fmaf(w, p0.y, acc[1]);
    acc[2] = fmaf(w, p1.x, acc[2]); acc[3] = fmaf(w, p1.y, acc[3]);
    acc[4] = fmaf(w, p2.x, acc[4]); acc[5] = fmaf(w, p2.y, acc[5]);
    acc[6] = fmaf(w, p3.x, acc[6]); acc[7] = fmaf(w, p3.y, acc[7]);
  }

  // ---- epilogue: normalize, head mean, bias, LN, ReLU ----
  float inv = 1.f / s;
  float t[8];
  #pragma unroll
  for (int i = 0; i < 8; ++i){
    float v = acc[i] * inv;
    v += __shfl_xor(v, 16);
    v += __shfl_xor(v, 32);
    t[i] = v * 0.25f;
  }
  int cb = (lane & 15) * 8;
  float4 b0 = *(const float4*)(bias + cb);
  float4 b1 = *(const float4*)(bias + cb + 4);
  t[0] += b0.x; t[1] += b0.y; t[2] += b0.z; t[3] += b0.w;
  t[4] += b1.x; t[5] += b1.y; t[6] += b1.z; t[7] += b1.w;
  float loc = t[0]+t[1]+t[2]+t[3]+t[4]+t[5]+t[6]+t[7];
  float mu = wsum(loc) * (1.f / 512.f);
  float sq = 0.f;
  #pragma unroll
  for (int i = 0; i < 8; ++i){ t[i] -= mu; sq += t[i] * t[i]; }
  float var = wsum(sq) * (1.f / 512.f);
  float invs = rsqrtf(var + LN_EPS);
  if (lane < 16){
    float4 g0 = *(const float4*)(lng + cb);
    float4 g1 = *(const float4*)(lng + cb + 4);
    float4 o0 = *(const float4*)(lnb + cb);
    float4 o1 = *(const float4*)(lnb + cb + 4);
    float o[8];
    o[0] = fmaxf(t[0]*invs*g0.x + o0.x, 0.f);
    o[1] = fmaxf(t[1]*invs*g0.y + o0.y, 0.f);
    o[2] = fmaxf(t[2]*invs*g0.z + o0.z, 0.f);
    o[3] = fmaxf(t[3]*invs*g0.w + o0.w, 0.f);
    o[4] = fmaxf(t[4]*invs*g1.x + o1.x, 0.f);
    o[5] = fmaxf(t[5]*invs*g1.y + o1.y, 0.f);
    o[6] = fmaxf(t[6]*invs*g1.z + o1.z, 0.f);
    o[7] = fmaxf(t[7]*invs*g1.w + o1.w, 0.f);
    float* xr = Xout + (size_t)n * HIDD + cb;
    *(float4*)xr       = make_float4(o[0], o[1], o[2], o[3]);
    *(float4*)(xr + 4) = make_float4(o[4], o[5], o[6], o[7]);
    uint4 pb;
    pb.x = pack2bf(o[0], o[1]); pb.y = pack2bf(o[2], o[3]);
    pb.z = pack2bf(o[4], o[5]); pb.w = pack2bf(o[6], o[7]);
    *(uint4*)(XoutBf + (size_t)n * HIDD + cb) = pb;
  }
}

// ---------------- global mean pool ----------------
__global__ __launch_bounds__(256) void k_pool(const float* __restrict__ X,
                                              const int* __restrict__ bnd,
                                              float* __restrict__ out){
  int g = blockIdx.x;
  int s = bnd[g], e = bnd[g + 1];
  int c = threadIdx.x & 127, part = threadIdx.x >> 7;
  float acc = 0.f;
  for (int n = s + part; n < e; n += 2) acc += X[(size_t)n * HIDD + c];
  __shared__ float red[256];
  red[threadIdx.x] = acc;
  __syncthreads();
  if (part == 0){
    out[g * HIDD + c] = (red[c] + red[128 + c]) / fmaxf((float)(e - s), 1.f);
  }
}

extern "C" void kernel_launch(void* const* d_in, const int* in_sizes, int n_in,
                              void* d_out, int out_size, void* d_ws, size_t ws_size,
                              hipStream_t stream){
  const float* x        = (const float*)d_in[0];
  const float* ea       = (const float*)d_in[1];
  const float* lin_w[3] = {(const float*)d_in[2], (const float*)d_in[3], (const float*)d_in[4]};
  const float* lin_edge = (const float*)d_in[5];
  const float* att_src  = (const float*)d_in[6];
  const float* att_dst  = (const float*)d_in[7];
  const float* att_edge = (const float*)d_in[8];
  const float* bias     = (const float*)d_in[9];
  const float* lng      = (const float*)d_in[10];
  const float* lnb      = (const float*)d_in[11];
  const int*   eidx     = (const int*)d_in[12];
  const int*   batch    = (const int*)d_in[13];
  const int*   srcp = eidx;
  const int*   dstp = eidx + N_EDG;

  char* ws = (char*)d_ws;
  size_t off = 0;
  auto alloc = [&](size_t bytes)->char*{
    size_t o = off;
    off = (off + bytes + 511) & ~(size_t)511;
    return ws + o;
  };
  int*   deg      = (int*)  alloc((size_t)N_NODES * 4);
  int*   rowptr   = (int*)  alloc((size_t)(N_NODES + 1) * 4);
  int*   cursor   = (int*)  alloc((size_t)N_NODES * 4);
  int*   csr_src  = (int*)  alloc((size_t)N_EDG * 4);
  int*   csr_dst  = (int*)  alloc((size_t)N_EDG * 4);
  int*   epos     = (int*)  alloc((size_t)N_EDG * 4);
  int*   bnd      = (int*)  alloc((size_t)(NB + 1) * 4);
  float* s_src    = (float*)alloc((size_t)N_NODES * 4 * 4);
  float* s_dst    = (float*)alloc((size_t)N_NODES * 4 * 4);
  float* al_loop  = (float*)alloc((size_t)N_NODES * 4 * 4);
  float* alpc     = (float*)alloc((size_t)N_EDG * 4 * 4);
  float* vfold    = (float*)alloc((size_t)3 * 1152 * 4);
  float* proj     = (float*)alloc((size_t)3 * N_NODES * 4 * 4);
  float* eaPc     = (float*)alloc((size_t)3 * N_EDG * 4 * 4);
  u16*   xbf0     = (u16*)  alloc((size_t)N_NODES * EMBD * 2);
  u16*   xbfA     = (u16*)  alloc((size_t)N_NODES * HIDD * 2);
  u16*   xbfB     = (u16*)  alloc((size_t)N_NODES * HIDD * 2);
  u16*   wt0      = (u16*)  alloc((size_t)OUTC * EMBD * 2);
  u16*   wt1      = (u16*)  alloc((size_t)OUTC * HIDD * 2);
  u16*   wt2      = (u16*)  alloc((size_t)OUTC * HIDD * 2);
  u16*   hbuf     = (u16*)  alloc((size_t)N_NODES * OUTC * 2);
  float* xA       = (float*)alloc((size_t)N_NODES * HIDD * 4);
  float* xB       = (float*)alloc((size_t)N_NODES * HIDD * 4);

  hipMemsetAsync(deg, 0, (size_t)N_NODES * 4, stream);
  k_deg<<<(N_EDG + 255) / 256, 256, 0, stream>>>(dstp, deg);
  k_scan<<<1, 1024, 0, stream>>>(deg, rowptr, cursor);
  k_scatter<<<(N_EDG + 255) / 256, 256, 0, stream>>>(srcp, dstp, cursor, csr_src, csr_dst, epos);
  k_bounds<<<(N_NODES + 255) / 256, 256, 0, stream>>>(batch, bnd);
  {
    dim3 fg(5, 3);
    k_fold<<<fg, 256, 0, stream>>>(lin_w[0], lin_w[1], lin_w[2], lin_edge,
                                   att_src, att_dst, att_edge, vfold);
  }
  k_cvt_x<<<(N_NODES * EMBD + 255) / 256, 256, 0, stream>>>(x, xbf0);
  {
    dim3 cg((OUTC * HIDD + 255) / 256, 3);
    k_cvt_w<<<cg, 256, 0, stream>>>(lin_w[0], lin_w[1], lin_w[2], wt0, wt1, wt2);
  }
  k_edgeproj<<<(N_EDG + 255) / 256, 256, 0, stream>>>(ea, epos, vfold, (float4*)eaPc);
  k_projsum<<<(N_NODES + 3) / 4, 256, 0, stream>>>((const float4*)eaPc, rowptr, (float4*)proj);

  const float* xcur = x;
  const u16* xbcur = xbf0;
  float* xout = xA;
  u16* xbout = xbfA;
  for (int L = 0; L < 3; ++L){
    int in_dim = L ? HIDD : EMBD;
    float* vf = vfold + L * 1152;
    const u16* wt = (L == 0) ? wt0 : ((L == 1) ? wt1 : wt2);
    dim3 gg(OUTC / 128, (N_NODES + 63) / 64);
    if (L == 0) k_gemm<EMBD><<<gg, 256, 0, stream>>>(xbcur, wt, hbuf, N_NODES);
    else        k_gemm<HIDD><<<gg, 256, 0, stream>>>(xbcur, wt, hbuf, N_NODES);
    k_nodelin<<<(N_NODES + 255) / 256, 256, 0, stream>>>(xcur, vf,
        (const float4*)(proj + (size_t)L * N_NODES * 4), deg,
        s_src, s_dst, al_loop, in_dim);
    k_edgepart<<<(N_EDG + 255) / 256, 256, 0, stream>>>(
        (const float4*)(eaPc + (size_t)L * N_EDG * 4), csr_src, csr_dst,
        (const float4*)s_src, (const float4*)s_dst, (float4*)alpc);
    k_aggr<<<(N_NODES + 3) / 4, 256, 0, stream>>>((const uint4*)hbuf,
        (const float4*)alpc, (const float4*)al_loop, rowptr, csr_src,
        bias + L * HIDD, lng + L * HIDD, lnb + L * HIDD, xout, xbout);
    xcur = xout; xbcur = xbout;
    xout = (L == 0) ? xB : xA;
    xbout = (L == 0) ? xbfB : xbfA;
  }

  k_pool<<<NB, 256, 0, stream>>>(xcur, bnd, (float*)d_out);
}

// Round 8
// 393.460 us; speedup vs baseline: 1.0945x; 1.0945x over previous
//
#include <hip/hip_runtime.h>
#include <math.h>

#define N_NODES 20000
#define N_EDG   320000
#define NB      64
#define EMBD    32
#define HIDD    128
#define NHEAD   4
#define OUTC    512      // H * HID
#define LN_EPS  1e-5f
#define NEG_SLOPE 0.2f

typedef unsigned int u32;
typedef unsigned short u16;
typedef __attribute__((ext_vector_type(8))) short s16x8;
typedef __attribute__((ext_vector_type(4))) float f32x4;

__device__ __forceinline__ float lrelu(float x){ return x >= 0.f ? x : NEG_SLOPE * x; }

__device__ __forceinline__ float2 bf2f(u32 p){
  float2 r;
  r.x = __uint_as_float(p << 16);
  r.y = __uint_as_float(p & 0xffff0000u);
  return r;
}
__device__ __forceinline__ u16 f2bf(float a){
  u32 ua = __float_as_uint(a);
  return (u16)((ua + 0x7fffu + ((ua >> 16) & 1u)) >> 16);
}
__device__ __forceinline__ u32 pack2bf(float a, float b){
  return (u32)f2bf(a) | ((u32)f2bf(b) << 16);
}

// ---------------- CSR construction ----------------
__global__ void k_deg(const int* __restrict__ dst, int* __restrict__ deg){
  int e = blockIdx.x * blockDim.x + threadIdx.x;
  if (e < N_EDG) atomicAdd(&deg[dst[e]], 1);
}

__global__ __launch_bounds__(1024) void k_scan(const int* __restrict__ deg,
                                               int* __restrict__ rowptr,
                                               int* __restrict__ cursor){
  __shared__ int sums[1024];
  const int CH = (N_NODES + 1023) / 1024;   // 20
  int t = threadIdx.x;
  int start = t * CH;
  int end = min(start + CH, N_NODES);
  int s = 0;
  for (int i = start; i < end; ++i) s += deg[i];
  sums[t] = s;
  __syncthreads();
  for (int off = 1; off < 1024; off <<= 1){
    int v = (t >= off) ? sums[t - off] : 0;
    __syncthreads();
    sums[t] += v;
    __syncthreads();
  }
  int run = (t > 0) ? sums[t - 1] : 0;
  for (int i = start; i < end; ++i){
    rowptr[i] = run; cursor[i] = run; run += deg[i];
  }
  if (t == 0) rowptr[N_NODES] = sums[1023];
}

__global__ void k_scatter(const int* __restrict__ src, const int* __restrict__ dst,
                          int* __restrict__ cursor,
                          int* __restrict__ csr_src, int* __restrict__ csr_dst,
                          int* __restrict__ epos){
  int e = blockIdx.x * blockDim.x + threadIdx.x;
  if (e < N_EDG){
    int d = dst[e];
    int p = atomicAdd(&cursor[d], 1);
    csr_src[p] = src[e];
    csr_dst[p] = d;
    epos[e] = p;
  }
}

// ---------------- fused setup: fold + cvt_w + cvt_x + bounds ----------------
// blocks [0,15): fold (5 per layer); [15,591): cvt_w; [591,3091): cvt_x; [3091,3170): bounds
__global__ __launch_bounds__(256) void k_setup(const float* __restrict__ W0,
                                               const float* __restrict__ W1,
                                               const float* __restrict__ W2,
                                               const float* __restrict__ lin_edge,
                                               const float* __restrict__ att_src,
                                               const float* __restrict__ att_dst,
                                               const float* __restrict__ att_edge,
                                               const float* __restrict__ x,
                                               const int* __restrict__ batch,
                                               float* __restrict__ vfold,
                                               u16* __restrict__ wt0, u16* __restrict__ wt1,
                                               u16* __restrict__ wt2, u16* __restrict__ xb,
                                               int* __restrict__ bnd){
  int b = blockIdx.x;
  if (b < 15){
    int L = b / 5;
    int in_dim = L ? HIDD : EMBD;
    const float* W  = (L == 0) ? W0 : ((L == 1) ? W1 : W2);
    const float* We = lin_edge + (size_t)L * EMBD * OUTC;
    const float* as = att_src + L * 512;
    const float* ad = att_dst + L * 512;
    const float* ae = att_edge + L * 512;
    float* vf = vfold + L * 1152;
    int j = (b % 5) * 256 + threadIdx.x;
    int nsrc = in_dim * NHEAD;
    if (j < nsrc){
      int k = j >> 2, h = j & 3;
      float s = 0.f;
      for (int c = 0; c < HIDD; ++c) s += W[k * OUTC + h * HIDD + c] * as[h * HIDD + c];
      vf[k * 4 + h] = s;
    } else if (j < 2 * nsrc){
      int jj = j - nsrc; int k = jj >> 2, h = jj & 3;
      float s = 0.f;
      for (int c = 0; c < HIDD; ++c) s += W[k * OUTC + h * HIDD + c] * ad[h * HIDD + c];
      vf[512 + k * 4 + h] = s;
    } else if (j < 2 * nsrc + EMBD * NHEAD){
      int jj = j - 2 * nsrc; int k = jj >> 2, h = jj & 3;
      float s = 0.f;
      for (int c = 0; c < HIDD; ++c) s += We[k * OUTC + h * HIDD + c] * ae[h * HIDD + c];
      vf[1024 + k * 4 + h] = s;
    }
  } else if (b < 591){
    int idx = (b - 15) * 256 + threadIdx.x;
    if (idx < 16384){
      int n = idx >> 5, k = idx & 31;
      wt0[idx] = f2bf(W0[(size_t)k * OUTC + n]);
    } else if (idx < 81920){
      int j = idx - 16384; int n = j >> 7, k = j & 127;
      wt1[j] = f2bf(W1[(size_t)k * OUTC + n]);
    } else {
      int j = idx - 81920; int n = j >> 7, k = j & 127;
      wt2[j] = f2bf(W2[(size_t)k * OUTC + n]);
    }
  } else if (b < 3091){
    int i = (b - 591) * 256 + threadIdx.x;
    if (i < N_NODES * EMBD) xb[i] = f2bf(x[i]);
  } else {
    int n = (b - 3091) * 256 + threadIdx.x;
    if (n >= N_NODES) return;
    int bb = batch[n];
    int bp = (n == 0) ? -1 : batch[n - 1];
    for (int g = bp + 1; g <= bb; ++g) bnd[g] = n;
    if (n == N_NODES - 1){
      for (int g = bb + 1; g <= NB; ++g) bnd[g] = N_NODES;
    }
  }
}

// ---------------- one-time edge projection: ea -> ev per layer, CSR order ----------------
__global__ __launch_bounds__(256) void k_edgeproj(const float* __restrict__ ea,
                                                  const int* __restrict__ epos,
                                                  const float* __restrict__ vfold,
                                                  float4* __restrict__ eaPc){
  __shared__ float vs[384];
  for (int i = threadIdx.x; i < 384; i += 256)
    vs[i] = vfold[(i >> 7) * 1152 + 1024 + (i & 127)];
  __syncthreads();
  int e = blockIdx.x * blockDim.x + threadIdx.x;
  if (e >= N_EDG) return;
  float4 a[8];
  const float4* er = (const float4*)(ea + (size_t)e * EMBD);
  #pragma unroll
  for (int i = 0; i < 8; ++i) a[i] = er[i];
  int p = epos[e];
  #pragma unroll
  for (int L = 0; L < 3; ++L){
    const float* v = vs + L * 128;
    float ev[4] = {0,0,0,0};
    #pragma unroll
    for (int q = 0; q < 8; ++q){
      #pragma unroll
      for (int h = 0; h < 4; ++h){
        ev[h] += a[q].x * v[(q*4+0)*4+h] + a[q].y * v[(q*4+1)*4+h]
               + a[q].z * v[(q*4+2)*4+h] + a[q].w * v[(q*4+3)*4+h];
      }
    }
    eaPc[(size_t)L * N_EDG + p] = make_float4(ev[0], ev[1], ev[2], ev[3]);
  }
}

__device__ __forceinline__ float wsum(float v){
  #pragma unroll
  for (int off = 32; off > 0; off >>= 1) v += __shfl_xor(v, off);
  return v;
}
__device__ __forceinline__ float wmax(float v){
  #pragma unroll
  for (int off = 32; off > 0; off >>= 1) v = fmaxf(v, __shfl_xor(v, off));
  return v;
}

__global__ __launch_bounds__(256) void k_projsum(const float4* __restrict__ eaPc,
                                                 const int* __restrict__ rowptr,
                                                 float4* __restrict__ proj){
  int wid = threadIdx.x >> 6, lane = threadIdx.x & 63;
  int n = blockIdx.x * 4 + wid;
  if (n >= N_NODES) return;
  int rs = rowptr[n], re = rowptr[n + 1];
  #pragma unroll
  for (int L = 0; L < 3; ++L){
    float a0 = 0.f, a1 = 0.f, a2 = 0.f, a3 = 0.f;
    for (int p = rs + lane; p < re; p += 64){
      float4 v = eaPc[(size_t)L * N_EDG + p];
      a0 += v.x; a1 += v.y; a2 += v.z; a3 += v.w;
    }
    a0 = wsum(a0); a1 = wsum(a1); a2 = wsum(a2); a3 = wsum(a3);
    if (lane == 0) proj[(size_t)L * N_NODES + n] = make_float4(a0, a1, a2, a3);
  }
}

// ---------------- MFMA bf16 GEMM ----------------
template<int K>
__global__ __launch_bounds__(256) void k_gemm(const u16* __restrict__ Xb,
                                              const u16* __restrict__ Wt,
                                              u16* __restrict__ Hb,
                                              int M){
  const int CH = K + 8;
  __shared__ u16 ldsA[64 * CH];
  __shared__ u16 ldsB[128 * CH];
  int bm = blockIdx.y * 64, bn = blockIdx.x * 128;
  int t = threadIdx.x;
  for (int f = t; f < 64 * (K / 8); f += 256){
    int row = f / (K / 8), c8 = f % (K / 8);
    int gm = bm + row;
    uint4 v = make_uint4(0, 0, 0, 0);
    if (gm < M) v = *(const uint4*)(Xb + (size_t)gm * K + c8 * 8);
    *(uint4*)&ldsA[row * CH + c8 * 8] = v;
  }
  for (int f = t; f < 128 * (K / 8); f += 256){
    int row = f / (K / 8), c8 = f % (K / 8);
    *(uint4*)&ldsB[row * CH + c8 * 8] = *(const uint4*)(Wt + (size_t)(bn + row) * K + c8 * 8);
  }
  __syncthreads();

  int w = t >> 6, lane = t & 63;
  int r = lane & 15, g = lane >> 4;
  f32x4 acc[8];
  #pragma unroll
  for (int i = 0; i < 8; ++i) acc[i] = (f32x4){0.f, 0.f, 0.f, 0.f};
  const u16* pa = &ldsA[(w * 16 + r) * CH + g * 8];
  #pragma unroll
  for (int k0 = 0; k0 < K; k0 += 32){
    s16x8 a = *(const s16x8*)(pa + k0);
    #pragma unroll
    for (int nf = 0; nf < 8; ++nf){
      s16x8 b = *(const s16x8*)(&ldsB[(nf * 16 + r) * CH + k0 + g * 8]);
      acc[nf] = __builtin_amdgcn_mfma_f32_16x16x32_bf16(a, b, acc[nf], 0, 0, 0);
    }
  }
  #pragma unroll
  for (int nf = 0; nf < 8; ++nf){
    #pragma unroll
    for (int i = 0; i < 4; ++i){
      int gm = bm + w * 16 + g * 4 + i;
      if (gm < M) Hb[(size_t)gm * OUTC + bn + nf * 16 + r] = f2bf(acc[nf][i]);
    }
  }
}

// ---------------- per-node logits: s_src, s_dst, self-loop logit ----------------
__global__ __launch_bounds__(256) void k_nodelin(const float* __restrict__ X,
                                                 const float* __restrict__ vfold,
                                                 const float4* __restrict__ projL,
                                                 const int* __restrict__ deg,
                                                 float* __restrict__ s_src, float* __restrict__ s_dst,
                                                 float* __restrict__ al_loop, int in_dim){
  __shared__ float vs[1024];
  for (int i = threadIdx.x; i < 1024; i += 256) vs[i] = vfold[i];
  __syncthreads();
  int n = blockIdx.x * blockDim.x + threadIdx.x;
  if (n >= N_NODES) return;
  float a[4] = {0,0,0,0}, d[4] = {0,0,0,0};
  const float* xr = X + (size_t)n * in_dim;
  for (int k4 = 0; k4 < in_dim; k4 += 4){
    float4 xv = *(const float4*)(xr + k4);
    #pragma unroll
    for (int h = 0; h < 4; ++h){
      a[h] += xv.x * vs[(k4+0)*4+h] + xv.y * vs[(k4+1)*4+h]
            + xv.z * vs[(k4+2)*4+h] + xv.w * vs[(k4+3)*4+h];
      d[h] += xv.x * vs[512+(k4+0)*4+h] + xv.y * vs[512+(k4+1)*4+h]
            + xv.z * vs[512+(k4+2)*4+h] + xv.w * vs[512+(k4+3)*4+h];
    }
  }
  float4 pj = projL[n];
  float invd = 1.f / fmaxf((float)deg[n], 1.f);
  ((float4*)s_src)[n] = make_float4(a[0], a[1], a[2], a[3]);
  ((float4*)s_dst)[n] = make_float4(d[0], d[1], d[2], d[3]);
  float4 ll;
  ll.x = lrelu(a[0]+d[0]+pj.x*invd); ll.y = lrelu(a[1]+d[1]+pj.y*invd);
  ll.z = lrelu(a[2]+d[2]+pj.z*invd); ll.w = lrelu(a[3]+d[3]+pj.w*invd);
  ((float4*)al_loop)[n] = ll;
}

// ---------------- per-edge logit (CSR position indexed, all streams coalesced) ----------------
__global__ __launch_bounds__(256) void k_edgepart(const float4* __restrict__ eaPcL,
                                                  const int* __restrict__ csr_src,
                                                  const int* __restrict__ csr_dst,
                                                  const float4* __restrict__ s_src4,
                                                  const float4* __restrict__ s_dst4,
                                                  float4* __restrict__ alpc){
  int p = blockIdx.x * blockDim.x + threadIdx.x;
  if (p >= N_EDG) return;
  float4 ev = eaPcL[p];
  float4 ss = s_src4[csr_src[p]];
  float4 dd = s_dst4[csr_dst[p]];
  float4 o;
  o.x = lrelu(ss.x + dd.x + ev.x);
  o.y = lrelu(ss.y + dd.y + ev.y);
  o.z = lrelu(ss.z + dd.z + ev.z);
  o.w = lrelu(ss.w + dd.w + ev.w);
  alpc[p] = o;
}

// ---------------- wave-per-node aggregation: 2-pass softmax, LDS-staged weights ----------------
__global__ __launch_bounds__(256) void k_aggr(const uint4* __restrict__ Hb4,
                                              const float4* __restrict__ alpc,
                                              const float4* __restrict__ al_loop,
                                              const int* __restrict__ rowptr,
                                              const int* __restrict__ csr_src,
                                              const float* __restrict__ bias,
                                              const float* __restrict__ lng,
                                              const float* __restrict__ lnb,
                                              float* __restrict__ Xout,
                                              u16* __restrict__ XoutBf){
  __shared__ float4 wlds4[4][64];
  __shared__ int    slds[4][64];
  int wid  = threadIdx.x >> 6;
  int lane = threadIdx.x & 63;
  int n = blockIdx.x * 4 + wid;
  if (n >= N_NODES) return;
  int h = lane >> 4;
  int rs = rowptr[n], re = rowptr[n + 1];

  float4 ll = al_loop[n];
  uint4 hv = Hb4[(size_t)n * 64 + lane];    // own row (prefetch)

  // ---- pass A: per-head max over edge logits (lane-parallel) ----
  float m0 = ll.x, m1 = ll.y, m2 = ll.z, m3 = ll.w;
  for (int p = rs + lane; p < re; p += 64){
    float4 v = alpc[p];
    m0 = fmaxf(m0, v.x); m1 = fmaxf(m1, v.y);
    m2 = fmaxf(m2, v.z); m3 = fmaxf(m3, v.w);
  }
  m0 = wmax(m0); m1 = wmax(m1); m2 = wmax(m2); m3 = wmax(m3);
  float mh  = (h == 0) ? m0 : ((h == 1) ? m1 : ((h == 2) ? m2 : m3));
  float llh = (h == 0) ? ll.x : ((h == 1) ? ll.y : ((h == 2) ? ll.z : ll.w));

  // ---- pass B: lane-parallel exp into LDS, static-address inner loop ----
  float s = __expf(llh - mh);               // self-loop weight
  float acc[8];
  { float2 p0 = bf2f(hv.x), p1 = bf2f(hv.y), p2 = bf2f(hv.z), p3 = bf2f(hv.w);
    acc[0]=s*p0.x; acc[1]=s*p0.y; acc[2]=s*p1.x; acc[3]=s*p1.y;
    acc[4]=s*p2.x; acc[5]=s*p2.y; acc[6]=s*p3.x; acc[7]=s*p3.y; }

  const float* wbase = (const float*)&wlds4[wid][0];
  for (int base = rs; base < re; base += 64){
    int cnt = min(64, re - base);
    if (lane < cnt){
      float4 v = alpc[base + lane];
      wlds4[wid][lane] = make_float4(__expf(v.x - m0), __expf(v.y - m1),
                                     __expf(v.z - m2), __expf(v.w - m3));
      slds[wid][lane] = csr_src[base + lane];
    }
    asm volatile("s_waitcnt lgkmcnt(0)" ::: "memory");
    #pragma unroll 4
    for (int jj = 0; jj < cnt; ++jj){
      float w = wbase[jj * 4 + h];          // ds_read broadcast (static addr)
      int  sj = slds[wid][jj];              // ds_read broadcast (static addr)
      s += w;
      uint4 hb = Hb4[(size_t)sj * 64 + lane];
      float2 p0 = bf2f(hb.x), p1 = bf2f(hb.y), p2 = bf2f(hb.z), p3 = bf2f(hb.w);
      acc[0] = fmaf(w, p0.x, acc[0]); acc[1] = fmaf(w, p0.y, acc[1]);
      acc[2] = fmaf(w, p1.x, acc[2]); acc[3] = fmaf(w, p1.y, acc[3]);
      acc[4] = fmaf(w, p2.x, acc[4]); acc[5] = fmaf(w, p2.y, acc[5]);
      acc[6] = fmaf(w, p3.x, acc[6]); acc[7] = fmaf(w, p3.y, acc[7]);
    }
    asm volatile("s_waitcnt lgkmcnt(0)" ::: "memory");
  }

  // ---- epilogue: normalize, head mean, bias, LN, ReLU ----
  float inv = 1.f / s;
  float t[8];
  #pragma unroll
  for (int i = 0; i < 8; ++i){
    float v = acc[i] * inv;
    v += __shfl_xor(v, 16);
    v += __shfl_xor(v, 32);
    t[i] = v * 0.25f;
  }
  int cb = (lane & 15) * 8;
  float4 b0 = *(const float4*)(bias + cb);
  float4 b1 = *(const float4*)(bias + cb + 4);
  t[0] += b0.x; t[1] += b0.y; t[2] += b0.z; t[3] += b0.w;
  t[4] += b1.x; t[5] += b1.y; t[6] += b1.z; t[7] += b1.w;
  float loc = t[0]+t[1]+t[2]+t[3]+t[4]+t[5]+t[6]+t[7];
  float mu = wsum(loc) * (1.f / 512.f);
  float sq = 0.f;
  #pragma unroll
  for (int i = 0; i < 8; ++i){ t[i] -= mu; sq += t[i] * t[i]; }
  float var = wsum(sq) * (1.f / 512.f);
  float invs = rsqrtf(var + LN_EPS);
  if (lane < 16){
    float4 g0 = *(const float4*)(lng + cb);
    float4 g1 = *(const float4*)(lng + cb + 4);
    float4 o0 = *(const float4*)(lnb + cb);
    float4 o1 = *(const float4*)(lnb + cb + 4);
    float o[8];
    o[0] = fmaxf(t[0]*invs*g0.x + o0.x, 0.f);
    o[1] = fmaxf(t[1]*invs*g0.y + o0.y, 0.f);
    o[2] = fmaxf(t[2]*invs*g0.z + o0.z, 0.f);
    o[3] = fmaxf(t[3]*invs*g0.w + o0.w, 0.f);
    o[4] = fmaxf(t[4]*invs*g1.x + o1.x, 0.f);
    o[5] = fmaxf(t[5]*invs*g1.y + o1.y, 0.f);
    o[6] = fmaxf(t[6]*invs*g1.z + o1.z, 0.f);
    o[7] = fmaxf(t[7]*invs*g1.w + o1.w, 0.f);
    float* xr = Xout + (size_t)n * HIDD + cb;
    *(float4*)xr       = make_float4(o[0], o[1], o[2], o[3]);
    *(float4*)(xr + 4) = make_float4(o[4], o[5], o[6], o[7]);
    uint4 pb;
    pb.x = pack2bf(o[0], o[1]); pb.y = pack2bf(o[2], o[3]);
    pb.z = pack2bf(o[4], o[5]); pb.w = pack2bf(o[6], o[7]);
    *(uint4*)(XoutBf + (size_t)n * HIDD + cb) = pb;
  }
}

// ---------------- global mean pool ----------------
__global__ __launch_bounds__(256) void k_pool(const float* __restrict__ X,
                                              const int* __restrict__ bnd,
                                              float* __restrict__ out){
  int g = blockIdx.x;
  int s = bnd[g], e = bnd[g + 1];
  int c = threadIdx.x & 127, part = threadIdx.x >> 7;
  float acc = 0.f;
  for (int n = s + part; n < e; n += 2) acc += X[(size_t)n * HIDD + c];
  __shared__ float red[256];
  red[threadIdx.x] = acc;
  __syncthreads();
  if (part == 0){
    out[g * HIDD + c] = (red[c] + red[128 + c]) / fmaxf((float)(e - s), 1.f);
  }
}

extern "C" void kernel_launch(void* const* d_in, const int* in_sizes, int n_in,
                              void* d_out, int out_size, void* d_ws, size_t ws_size,
                              hipStream_t stream){
  const float* x        = (const float*)d_in[0];
  const float* ea       = (const float*)d_in[1];
  const float* lin_w[3] = {(const float*)d_in[2], (const float*)d_in[3], (const float*)d_in[4]};
  const float* lin_edge = (const float*)d_in[5];
  const float* att_src  = (const float*)d_in[6];
  const float* att_dst  = (const float*)d_in[7];
  const float* att_edge = (const float*)d_in[8];
  const float* bias     = (const float*)d_in[9];
  const float* lng      = (const float*)d_in[10];
  const float* lnb      = (const float*)d_in[11];
  const int*   eidx     = (const int*)d_in[12];
  const int*   batch    = (const int*)d_in[13];
  const int*   srcp = eidx;
  const int*   dstp = eidx + N_EDG;

  char* ws = (char*)d_ws;
  size_t off = 0;
  auto alloc = [&](size_t bytes)->char*{
    size_t o = off;
    off = (off + bytes + 511) & ~(size_t)511;
    return ws + o;
  };
  int*   deg      = (int*)  alloc((size_t)N_NODES * 4);
  int*   rowptr   = (int*)  alloc((size_t)(N_NODES + 1) * 4);
  int*   cursor   = (int*)  alloc((size_t)N_NODES * 4);
  int*   csr_src  = (int*)  alloc((size_t)N_EDG * 4);
  int*   csr_dst  = (int*)  alloc((size_t)N_EDG * 4);
  int*   epos     = (int*)  alloc((size_t)N_EDG * 4);
  int*   bnd      = (int*)  alloc((size_t)(NB + 1) * 4);
  float* s_src    = (float*)alloc((size_t)N_NODES * 4 * 4);
  float* s_dst    = (float*)alloc((size_t)N_NODES * 4 * 4);
  float* al_loop  = (float*)alloc((size_t)N_NODES * 4 * 4);
  float* alpc     = (float*)alloc((size_t)N_EDG * 4 * 4);
  float* vfold    = (float*)alloc((size_t)3 * 1152 * 4);
  float* proj     = (float*)alloc((size_t)3 * N_NODES * 4 * 4);
  float* eaPc     = (float*)alloc((size_t)3 * N_EDG * 4 * 4);
  u16*   xbf0     = (u16*)  alloc((size_t)N_NODES * EMBD * 2);
  u16*   xbfA     = (u16*)  alloc((size_t)N_NODES * HIDD * 2);
  u16*   xbfB     = (u16*)  alloc((size_t)N_NODES * HIDD * 2);
  u16*   wt0      = (u16*)  alloc((size_t)OUTC * EMBD * 2);
  u16*   wt1      = (u16*)  alloc((size_t)OUTC * HIDD * 2);
  u16*   wt2      = (u16*)  alloc((size_t)OUTC * HIDD * 2);
  u16*   hbuf     = (u16*)  alloc((size_t)N_NODES * OUTC * 2);
  float* xA       = (float*)alloc((size_t)N_NODES * HIDD * 4);
  float* xB       = (float*)alloc((size_t)N_NODES * HIDD * 4);

  hipMemsetAsync(deg, 0, (size_t)N_NODES * 4, stream);
  k_setup<<<3170, 256, 0, stream>>>(lin_w[0], lin_w[1], lin_w[2], lin_edge,
                                    att_src, att_dst, att_edge, x, batch,
                                    vfold, wt0, wt1, wt2, xbf0, bnd);
  k_deg<<<(N_EDG + 255) / 256, 256, 0, stream>>>(dstp, deg);
  k_scan<<<1, 1024, 0, stream>>>(deg, rowptr, cursor);
  k_scatter<<<(N_EDG + 255) / 256, 256, 0, stream>>>(srcp, dstp, cursor, csr_src, csr_dst, epos);
  k_edgeproj<<<(N_EDG + 255) / 256, 256, 0, stream>>>(ea, epos, vfold, (float4*)eaPc);
  k_projsum<<<(N_NODES + 3) / 4, 256, 0, stream>>>((const float4*)eaPc, rowptr, (float4*)proj);

  const float* xcur = x;
  const u16* xbcur = xbf0;
  float* xout = xA;
  u16* xbout = xbfA;
  for (int L = 0; L < 3; ++L){
    int in_dim = L ? HIDD : EMBD;
    float* vf = vfold + L * 1152;
    const u16* wt = (L == 0) ? wt0 : ((L == 1) ? wt1 : wt2);
    dim3 gg(OUTC / 128, (N_NODES + 63) / 64);
    if (L == 0) k_gemm<EMBD><<<gg, 256, 0, stream>>>(xbcur, wt, hbuf, N_NODES);
    else        k_gemm<HIDD><<<gg, 256, 0, stream>>>(xbcur, wt, hbuf, N_NODES);
    k_nodelin<<<(N_NODES + 255) / 256, 256, 0, stream>>>(xcur, vf,
        (const float4*)(proj + (size_t)L * N_NODES * 4), deg,
        s_src, s_dst, al_loop, in_dim);
    k_edgepart<<<(N_EDG + 255) / 256, 256, 0, stream>>>(
        (const float4*)(eaPc + (size_t)L * N_EDG * 4), csr_src, csr_dst,
        (const float4*)s_src, (const float4*)s_dst, (float4*)alpc);
    k_aggr<<<(N_NODES + 3) / 4, 256, 0, stream>>>((const uint4*)hbuf,
        (const float4*)alpc, (const float4*)al_loop, rowptr, csr_src,
        bias + L * HIDD, lng + L * HIDD, lnb + L * HIDD, xout, xbout);
    xcur = xout; xbcur = xbout;
    xout = (L == 0) ? xB : xA;
    xbout = (L == 0) ? xbfB : xbfA;
  }

  k_pool<<<NB, 256, 0, stream>>>(xcur, bnd, (float*)d_out);
}

// Round 9
// 383.312 us; speedup vs baseline: 1.1235x; 1.0265x over previous
//
#include <hip/hip_runtime.h>
#include <math.h>

#define N_NODES 20000
#define N_EDG   320000
#define NB      64
#define EMBD    32
#define HIDD    128
#define NHEAD   4
#define OUTC    512      // H * HID
#define LN_EPS  1e-5f
#define NEG_SLOPE 0.2f

typedef unsigned int u32;
typedef unsigned short u16;
typedef __attribute__((ext_vector_type(8))) short s16x8;
typedef __attribute__((ext_vector_type(4))) float f32x4;

__device__ __forceinline__ float lrelu(float x){ return x >= 0.f ? x : NEG_SLOPE * x; }

__device__ __forceinline__ float2 bf2f(u32 p){
  float2 r;
  r.x = __uint_as_float(p << 16);
  r.y = __uint_as_float(p & 0xffff0000u);
  return r;
}
__device__ __forceinline__ u16 f2bf(float a){
  u32 ua = __float_as_uint(a);
  return (u16)((ua + 0x7fffu + ((ua >> 16) & 1u)) >> 16);
}
__device__ __forceinline__ u32 pack2bf(float a, float b){
  return (u32)f2bf(a) | ((u32)f2bf(b) << 16);
}

// ---------------- CSR construction ----------------
__global__ void k_deg(const int* __restrict__ dst, int* __restrict__ deg){
  int e = blockIdx.x * blockDim.x + threadIdx.x;
  if (e < N_EDG) atomicAdd(&deg[dst[e]], 1);
}

__global__ __launch_bounds__(1024) void k_scan(const int* __restrict__ deg,
                                               int* __restrict__ rowptr,
                                               int* __restrict__ cursor){
  __shared__ int sums[1024];
  const int CH = (N_NODES + 1023) / 1024;   // 20
  int t = threadIdx.x;
  int start = t * CH;
  int end = min(start + CH, N_NODES);
  int s = 0;
  for (int i = start; i < end; ++i) s += deg[i];
  sums[t] = s;
  __syncthreads();
  for (int off = 1; off < 1024; off <<= 1){
    int v = (t >= off) ? sums[t - off] : 0;
    __syncthreads();
    sums[t] += v;
    __syncthreads();
  }
  int run = (t > 0) ? sums[t - 1] : 0;
  for (int i = start; i < end; ++i){
    rowptr[i] = run; cursor[i] = run; run += deg[i];
  }
  if (t == 0) rowptr[N_NODES] = sums[1023];
}

__global__ void k_scatter(const int* __restrict__ src, const int* __restrict__ dst,
                          int* __restrict__ cursor,
                          int* __restrict__ csr_src, int* __restrict__ epos){
  int e = blockIdx.x * blockDim.x + threadIdx.x;
  if (e < N_EDG){
    int d = dst[e];
    int p = atomicAdd(&cursor[d], 1);
    csr_src[p] = src[e];
    epos[e] = p;
  }
}

// ---------------- fused setup: fold + cvt_w + cvt_x + bounds ----------------
// blocks [0,15): fold (5 per layer); [15,591): cvt_w; [591,3091): cvt_x; [3091,3170): bounds
__global__ __launch_bounds__(256) void k_setup(const float* __restrict__ W0,
                                               const float* __restrict__ W1,
                                               const float* __restrict__ W2,
                                               const float* __restrict__ lin_edge,
                                               const float* __restrict__ att_src,
                                               const float* __restrict__ att_dst,
                                               const float* __restrict__ att_edge,
                                               const float* __restrict__ x,
                                               const int* __restrict__ batch,
                                               float* __restrict__ vfold,
                                               u16* __restrict__ wt0, u16* __restrict__ wt1,
                                               u16* __restrict__ wt2, u16* __restrict__ xb,
                                               int* __restrict__ bnd){
  int b = blockIdx.x;
  if (b < 15){
    int L = b / 5;
    int in_dim = L ? HIDD : EMBD;
    const float* W  = (L == 0) ? W0 : ((L == 1) ? W1 : W2);
    const float* We = lin_edge + (size_t)L * EMBD * OUTC;
    const float* as = att_src + L * 512;
    const float* ad = att_dst + L * 512;
    const float* ae = att_edge + L * 512;
    float* vf = vfold + L * 1152;
    int j = (b % 5) * 256 + threadIdx.x;
    int nsrc = in_dim * NHEAD;
    if (j < nsrc){
      int k = j >> 2, h = j & 3;
      float s = 0.f;
      for (int c = 0; c < HIDD; ++c) s += W[k * OUTC + h * HIDD + c] * as[h * HIDD + c];
      vf[k * 4 + h] = s;
    } else if (j < 2 * nsrc){
      int jj = j - nsrc; int k = jj >> 2, h = jj & 3;
      float s = 0.f;
      for (int c = 0; c < HIDD; ++c) s += W[k * OUTC + h * HIDD + c] * ad[h * HIDD + c];
      vf[512 + k * 4 + h] = s;
    } else if (j < 2 * nsrc + EMBD * NHEAD){
      int jj = j - 2 * nsrc; int k = jj >> 2, h = jj & 3;
      float s = 0.f;
      for (int c = 0; c < HIDD; ++c) s += We[k * OUTC + h * HIDD + c] * ae[h * HIDD + c];
      vf[1024 + k * 4 + h] = s;
    }
  } else if (b < 591){
    int idx = (b - 15) * 256 + threadIdx.x;
    if (idx < 16384){
      int n = idx >> 5, k = idx & 31;
      wt0[idx] = f2bf(W0[(size_t)k * OUTC + n]);
    } else if (idx < 81920){
      int j = idx - 16384; int n = j >> 7, k = j & 127;
      wt1[j] = f2bf(W1[(size_t)k * OUTC + n]);
    } else {
      int j = idx - 81920; int n = j >> 7, k = j & 127;
      wt2[j] = f2bf(W2[(size_t)k * OUTC + n]);
    }
  } else if (b < 3091){
    int i = (b - 591) * 256 + threadIdx.x;
    if (i < N_NODES * EMBD) xb[i] = f2bf(x[i]);
  } else {
    int n = (b - 3091) * 256 + threadIdx.x;
    if (n >= N_NODES) return;
    int bb = batch[n];
    int bp = (n == 0) ? -1 : batch[n - 1];
    for (int g = bp + 1; g <= bb; ++g) bnd[g] = n;
    if (n == N_NODES - 1){
      for (int g = bb + 1; g <= NB; ++g) bnd[g] = N_NODES;
    }
  }
}

// ---------------- one-time edge projection: ea -> ev per layer, CSR order ----------------
__global__ __launch_bounds__(256) void k_edgeproj(const float* __restrict__ ea,
                                                  const int* __restrict__ epos,
                                                  const float* __restrict__ vfold,
                                                  float4* __restrict__ eaPc){
  __shared__ float vs[384];
  for (int i = threadIdx.x; i < 384; i += 256)
    vs[i] = vfold[(i >> 7) * 1152 + 1024 + (i & 127)];
  __syncthreads();
  int e = blockIdx.x * blockDim.x + threadIdx.x;
  if (e >= N_EDG) return;
  float4 a[8];
  const float4* er = (const float4*)(ea + (size_t)e * EMBD);
  #pragma unroll
  for (int i = 0; i < 8; ++i) a[i] = er[i];
  int p = epos[e];
  #pragma unroll
  for (int L = 0; L < 3; ++L){
    const float* v = vs + L * 128;
    float ev[4] = {0,0,0,0};
    #pragma unroll
    for (int q = 0; q < 8; ++q){
      #pragma unroll
      for (int h = 0; h < 4; ++h){
        ev[h] += a[q].x * v[(q*4+0)*4+h] + a[q].y * v[(q*4+1)*4+h]
               + a[q].z * v[(q*4+2)*4+h] + a[q].w * v[(q*4+3)*4+h];
      }
    }
    eaPc[(size_t)L * N_EDG + p] = make_float4(ev[0], ev[1], ev[2], ev[3]);
  }
}

__device__ __forceinline__ float wsum(float v){
  #pragma unroll
  for (int off = 32; off > 0; off >>= 1) v += __shfl_xor(v, off);
  return v;
}
__device__ __forceinline__ float wmax(float v){
  #pragma unroll
  for (int off = 32; off > 0; off >>= 1) v = fmaxf(v, __shfl_xor(v, off));
  return v;
}

__global__ __launch_bounds__(256) void k_projsum(const float4* __restrict__ eaPc,
                                                 const int* __restrict__ rowptr,
                                                 float4* __restrict__ proj){
  int wid = threadIdx.x >> 6, lane = threadIdx.x & 63;
  int n = blockIdx.x * 4 + wid;
  if (n >= N_NODES) return;
  int rs = rowptr[n], re = rowptr[n + 1];
  #pragma unroll
  for (int L = 0; L < 3; ++L){
    float a0 = 0.f, a1 = 0.f, a2 = 0.f, a3 = 0.f;
    for (int p = rs + lane; p < re; p += 64){
      float4 v = eaPc[(size_t)L * N_EDG + p];
      a0 += v.x; a1 += v.y; a2 += v.z; a3 += v.w;
    }
    a0 = wsum(a0); a1 = wsum(a1); a2 = wsum(a2); a3 = wsum(a3);
    if (lane == 0) proj[(size_t)L * N_NODES + n] = make_float4(a0, a1, a2, a3);
  }
}

// ---------------- MFMA bf16 GEMM ----------------
template<int K>
__global__ __launch_bounds__(256) void k_gemm(const u16* __restrict__ Xb,
                                              const u16* __restrict__ Wt,
                                              u16* __restrict__ Hb,
                                              int M){
  const int CH = K + 8;
  __shared__ u16 ldsA[64 * CH];
  __shared__ u16 ldsB[128 * CH];
  int bm = blockIdx.y * 64, bn = blockIdx.x * 128;
  int t = threadIdx.x;
  for (int f = t; f < 64 * (K / 8); f += 256){
    int row = f / (K / 8), c8 = f % (K / 8);
    int gm = bm + row;
    uint4 v = make_uint4(0, 0, 0, 0);
    if (gm < M) v = *(const uint4*)(Xb + (size_t)gm * K + c8 * 8);
    *(uint4*)&ldsA[row * CH + c8 * 8] = v;
  }
  for (int f = t; f < 128 * (K / 8); f += 256){
    int row = f / (K / 8), c8 = f % (K / 8);
    *(uint4*)&ldsB[row * CH + c8 * 8] = *(const uint4*)(Wt + (size_t)(bn + row) * K + c8 * 8);
  }
  __syncthreads();

  int w = t >> 6, lane = t & 63;
  int r = lane & 15, g = lane >> 4;
  f32x4 acc[8];
  #pragma unroll
  for (int i = 0; i < 8; ++i) acc[i] = (f32x4){0.f, 0.f, 0.f, 0.f};
  const u16* pa = &ldsA[(w * 16 + r) * CH + g * 8];
  #pragma unroll
  for (int k0 = 0; k0 < K; k0 += 32){
    s16x8 a = *(const s16x8*)(pa + k0);
    #pragma unroll
    for (int nf = 0; nf < 8; ++nf){
      s16x8 b = *(const s16x8*)(&ldsB[(nf * 16 + r) * CH + k0 + g * 8]);
      acc[nf] = __builtin_amdgcn_mfma_f32_16x16x32_bf16(a, b, acc[nf], 0, 0, 0);
    }
  }
  #pragma unroll
  for (int nf = 0; nf < 8; ++nf){
    #pragma unroll
    for (int i = 0; i < 4; ++i){
      int gm = bm + w * 16 + g * 4 + i;
      if (gm < M) Hb[(size_t)gm * OUTC + bn + nf * 16 + r] = f2bf(acc[nf][i]);
    }
  }
}

// ---------------- per-node logits: s_src, s_dst, self-loop logit ----------------
__global__ __launch_bounds__(256) void k_nodelin(const float* __restrict__ X,
                                                 const float* __restrict__ vfold,
                                                 const float4* __restrict__ projL,
                                                 const int* __restrict__ deg,
                                                 float* __restrict__ s_src, float* __restrict__ s_dst,
                                                 float* __restrict__ al_loop, int in_dim){
  __shared__ float vs[1024];
  for (int i = threadIdx.x; i < 1024; i += 256) vs[i] = vfold[i];
  __syncthreads();
  int n = blockIdx.x * blockDim.x + threadIdx.x;
  if (n >= N_NODES) return;
  float a[4] = {0,0,0,0}, d[4] = {0,0,0,0};
  const float* xr = X + (size_t)n * in_dim;
  for (int k4 = 0; k4 < in_dim; k4 += 4){
    float4 xv = *(const float4*)(xr + k4);
    #pragma unroll
    for (int h = 0; h < 4; ++h){
      a[h] += xv.x * vs[(k4+0)*4+h] + xv.y * vs[(k4+1)*4+h]
            + xv.z * vs[(k4+2)*4+h] + xv.w * vs[(k4+3)*4+h];
      d[h] += xv.x * vs[512+(k4+0)*4+h] + xv.y * vs[512+(k4+1)*4+h]
            + xv.z * vs[512+(k4+2)*4+h] + xv.w * vs[512+(k4+3)*4+h];
    }
  }
  float4 pj = projL[n];
  float invd = 1.f / fmaxf((float)deg[n], 1.f);
  ((float4*)s_src)[n] = make_float4(a[0], a[1], a[2], a[3]);
  ((float4*)s_dst)[n] = make_float4(d[0], d[1], d[2], d[3]);
  float4 ll;
  ll.x = lrelu(a[0]+d[0]+pj.x*invd); ll.y = lrelu(a[1]+d[1]+pj.y*invd);
  ll.z = lrelu(a[2]+d[2]+pj.z*invd); ll.w = lrelu(a[3]+d[3]+pj.w*invd);
  ((float4*)al_loop)[n] = ll;
}

// ---------------- wave-per-node aggregation: inline logits, 2-pass softmax, LDS-staged weights ----------------
__global__ __launch_bounds__(256) void k_aggr(const uint4* __restrict__ Hb4,
                                              const float4* __restrict__ eaPcL,
                                              const float4* __restrict__ s_src4,
                                              const float4* __restrict__ s_dst4,
                                              const float4* __restrict__ al_loop,
                                              const int* __restrict__ rowptr,
                                              const int* __restrict__ csr_src,
                                              const float* __restrict__ bias,
                                              const float* __restrict__ lng,
                                              const float* __restrict__ lnb,
                                              float* __restrict__ Xout,
                                              u16* __restrict__ XoutBf){
  __shared__ float4 wlds4[4][64];
  __shared__ int    slds[4][64];
  int wid  = threadIdx.x >> 6;
  int lane = threadIdx.x & 63;
  int n = blockIdx.x * 4 + wid;
  if (n >= N_NODES) return;
  int h = lane >> 4;
  int rs = rowptr[n], re = rowptr[n + 1];

  float4 ll = al_loop[n];
  float4 dd = s_dst4[n];
  uint4 hv = Hb4[(size_t)n * 64 + lane];    // own row (prefetch)

  // ---- pass A: inline logits, per-head max (lane-parallel) ----
  float m0 = ll.x, m1 = ll.y, m2 = ll.z, m3 = ll.w;
  for (int p = rs + lane; p < re; p += 64){
    float4 ev = eaPcL[p];                   // coalesced
    int sj = csr_src[p];                    // coalesced
    float4 ss = s_src4[sj];                 // random 16B, L2-resident (320 KB)
    m0 = fmaxf(m0, lrelu(ss.x + dd.x + ev.x));
    m1 = fmaxf(m1, lrelu(ss.y + dd.y + ev.y));
    m2 = fmaxf(m2, lrelu(ss.z + dd.z + ev.z));
    m3 = fmaxf(m3, lrelu(ss.w + dd.w + ev.w));
  }
  m0 = wmax(m0); m1 = wmax(m1); m2 = wmax(m2); m3 = wmax(m3);
  float mh  = (h == 0) ? m0 : ((h == 1) ? m1 : ((h == 2) ? m2 : m3));
  float llh = (h == 0) ? ll.x : ((h == 1) ? ll.y : ((h == 2) ? ll.z : ll.w));

  // ---- pass B: recompute logits (L2-hot), lane-parallel exp into LDS, static-address inner loop ----
  float s = __expf(llh - mh);               // self-loop weight
  float acc[8];
  { float2 p0 = bf2f(hv.x), p1 = bf2f(hv.y), p2 = bf2f(hv.z), p3 = bf2f(hv.w);
    acc[0]=s*p0.x; acc[1]=s*p0.y; acc[2]=s*p1.x; acc[3]=s*p1.y;
    acc[4]=s*p2.x; acc[5]=s*p2.y; acc[6]=s*p3.x; acc[7]=s*p3.y; }

  const float* wbase = (const float*)&wlds4[wid][0];
  for (int base = rs; base < re; base += 64){
    int cnt = min(64, re - base);
    if (lane < cnt){
      float4 ev = eaPcL[base + lane];
      int sj = csr_src[base + lane];
      float4 ss = s_src4[sj];
      float vx = lrelu(ss.x + dd.x + ev.x);
      float vy = lrelu(ss.y + dd.y + ev.y);
      float vz = lrelu(ss.z + dd.z + ev.z);
      float vw = lrelu(ss.w + dd.w + ev.w);
      wlds4[wid][lane] = make_float4(__expf(vx - m0), __expf(vy - m1),
                                     __expf(vz - m2), __expf(vw - m3));
      slds[wid][lane] = sj;
    }
    asm volatile("s_waitcnt lgkmcnt(0)" ::: "memory");
    #pragma unroll 4
    for (int jj = 0; jj < cnt; ++jj){
      float w = wbase[jj * 4 + h];          // ds_read broadcast (static addr)
      int  sj = slds[wid][jj];              // ds_read broadcast (static addr)
      s += w;
      uint4 hb = Hb4[(size_t)sj * 64 + lane];
      float2 p0 = bf2f(hb.x), p1 = bf2f(hb.y), p2 = bf2f(hb.z), p3 = bf2f(hb.w);
      acc[0] = fmaf(w, p0.x, acc[0]); acc[1] = fmaf(w, p0.y, acc[1]);
      acc[2] = fmaf(w, p1.x, acc[2]); acc[3] = fmaf(w, p1.y, acc[3]);
      acc[4] = fmaf(w, p2.x, acc[4]); acc[5] = fmaf(w, p2.y, acc[5]);
      acc[6] = fmaf(w, p3.x, acc[6]); acc[7] = fmaf(w, p3.y, acc[7]);
    }
    asm volatile("s_waitcnt lgkmcnt(0)" ::: "memory");
  }

  // ---- epilogue: normalize, head mean, bias, LN, ReLU ----
  float inv = 1.f / s;
  float t[8];
  #pragma unroll
  for (int i = 0; i < 8; ++i){
    float v = acc[i] * inv;
    v += __shfl_xor(v, 16);
    v += __shfl_xor(v, 32);
    t[i] = v * 0.25f;
  }
  int cb = (lane & 15) * 8;
  float4 b0 = *(const float4*)(bias + cb);
  float4 b1 = *(const float4*)(bias + cb + 4);
  t[0] += b0.x; t[1] += b0.y; t[2] += b0.z; t[3] += b0.w;
  t[4] += b1.x; t[5] += b1.y; t[6] += b1.z; t[7] += b1.w;
  float loc = t[0]+t[1]+t[2]+t[3]+t[4]+t[5]+t[6]+t[7];
  float mu = wsum(loc) * (1.f / 512.f);
  float sq = 0.f;
  #pragma unroll
  for (int i = 0; i < 8; ++i){ t[i] -= mu; sq += t[i] * t[i]; }
  float var = wsum(sq) * (1.f / 512.f);
  float invs = rsqrtf(var + LN_EPS);
  if (lane < 16){
    float4 g0 = *(const float4*)(lng + cb);
    float4 g1 = *(const float4*)(lng + cb + 4);
    float4 o0 = *(const float4*)(lnb + cb);
    float4 o1 = *(const float4*)(lnb + cb + 4);
    float o[8];
    o[0] = fmaxf(t[0]*invs*g0.x + o0.x, 0.f);
    o[1] = fmaxf(t[1]*invs*g0.y + o0.y, 0.f);
    o[2] = fmaxf(t[2]*invs*g0.z + o0.z, 0.f);
    o[3] = fmaxf(t[3]*invs*g0.w + o0.w, 0.f);
    o[4] = fmaxf(t[4]*invs*g1.x + o1.x, 0.f);
    o[5] = fmaxf(t[5]*invs*g1.y + o1.y, 0.f);
    o[6] = fmaxf(t[6]*invs*g1.z + o1.z, 0.f);
    o[7] = fmaxf(t[7]*invs*g1.w + o1.w, 0.f);
    float* xr = Xout + (size_t)n * HIDD + cb;
    *(float4*)xr       = make_float4(o[0], o[1], o[2], o[3]);
    *(float4*)(xr + 4) = make_float4(o[4], o[5], o[6], o[7]);
    uint4 pb;
    pb.x = pack2bf(o[0], o[1]); pb.y = pack2bf(o[2], o[3]);
    pb.z = pack2bf(o[4], o[5]); pb.w = pack2bf(o[6], o[7]);
    *(uint4*)(XoutBf + (size_t)n * HIDD + cb) = pb;
  }
}

// ---------------- global mean pool ----------------
__global__ __launch_bounds__(256) void k_pool(const float* __restrict__ X,
                                              const int* __restrict__ bnd,
                                              float* __restrict__ out){
  int g = blockIdx.x;
  int s = bnd[g], e = bnd[g + 1];
  int c = threadIdx.x & 127, part = threadIdx.x >> 7;
  float acc = 0.f;
  for (int n = s + part; n < e; n += 2) acc += X[(size_t)n * HIDD + c];
  __shared__ float red[256];
  red[threadIdx.x] = acc;
  __syncthreads();
  if (part == 0){
    out[g * HIDD + c] = (red[c] + red[128 + c]) / fmaxf((float)(e - s), 1.f);
  }
}

extern "C" void kernel_launch(void* const* d_in, const int* in_sizes, int n_in,
                              void* d_out, int out_size, void* d_ws, size_t ws_size,
                              hipStream_t stream){
  const float* x        = (const float*)d_in[0];
  const float* ea       = (const float*)d_in[1];
  const float* lin_w[3] = {(const float*)d_in[2], (const float*)d_in[3], (const float*)d_in[4]};
  const float* lin_edge = (const float*)d_in[5];
  const float* att_src  = (const float*)d_in[6];
  const float* att_dst  = (const float*)d_in[7];
  const float* att_edge = (const float*)d_in[8];
  const float* bias     = (const float*)d_in[9];
  const float* lng      = (const float*)d_in[10];
  const float* lnb      = (const float*)d_in[11];
  const int*   eidx     = (const int*)d_in[12];
  const int*   batch    = (const int*)d_in[13];
  const int*   srcp = eidx;
  const int*   dstp = eidx + N_EDG;

  char* ws = (char*)d_ws;
  size_t off = 0;
  auto alloc = [&](size_t bytes)->char*{
    size_t o = off;
    off = (off + bytes + 511) & ~(size_t)511;
    return ws + o;
  };
  int*   deg      = (int*)  alloc((size_t)N_NODES * 4);
  int*   rowptr   = (int*)  alloc((size_t)(N_NODES + 1) * 4);
  int*   cursor   = (int*)  alloc((size_t)N_NODES * 4);
  int*   csr_src  = (int*)  alloc((size_t)N_EDG * 4);
  int*   epos     = (int*)  alloc((size_t)N_EDG * 4);
  int*   bnd      = (int*)  alloc((size_t)(NB + 1) * 4);
  float* s_src    = (float*)alloc((size_t)N_NODES * 4 * 4);
  float* s_dst    = (float*)alloc((size_t)N_NODES * 4 * 4);
  float* al_loop  = (float*)alloc((size_t)N_NODES * 4 * 4);
  float* vfold    = (float*)alloc((size_t)3 * 1152 * 4);
  float* proj     = (float*)alloc((size_t)3 * N_NODES * 4 * 4);
  float* eaPc     = (float*)alloc((size_t)3 * N_EDG * 4 * 4);
  u16*   xbf0     = (u16*)  alloc((size_t)N_NODES * EMBD * 2);
  u16*   xbfA     = (u16*)  alloc((size_t)N_NODES * HIDD * 2);
  u16*   xbfB     = (u16*)  alloc((size_t)N_NODES * HIDD * 2);
  u16*   wt0      = (u16*)  alloc((size_t)OUTC * EMBD * 2);
  u16*   wt1      = (u16*)  alloc((size_t)OUTC * HIDD * 2);
  u16*   wt2      = (u16*)  alloc((size_t)OUTC * HIDD * 2);
  u16*   hbuf     = (u16*)  alloc((size_t)N_NODES * OUTC * 2);
  float* xA       = (float*)alloc((size_t)N_NODES * HIDD * 4);
  float* xB       = (float*)alloc((size_t)N_NODES * HIDD * 4);

  hipMemsetAsync(deg, 0, (size_t)N_NODES * 4, stream);
  k_setup<<<3170, 256, 0, stream>>>(lin_w[0], lin_w[1], lin_w[2], lin_edge,
                                    att_src, att_dst, att_edge, x, batch,
                                    vfold, wt0, wt1, wt2, xbf0, bnd);
  k_deg<<<(N_EDG + 255) / 256, 256, 0, stream>>>(dstp, deg);
  k_scan<<<1, 1024, 0, stream>>>(deg, rowptr, cursor);
  k_scatter<<<(N_EDG + 255) / 256, 256, 0, stream>>>(srcp, dstp, cursor, csr_src, epos);
  k_edgeproj<<<(N_EDG + 255) / 256, 256, 0, stream>>>(ea, epos, vfold, (float4*)eaPc);
  k_projsum<<<(N_NODES + 3) / 4, 256, 0, stream>>>((const float4*)eaPc, rowptr, (float4*)proj);

  const float* xcur = x;
  const u16* xbcur = xbf0;
  float* xout = xA;
  u16* xbout = xbfA;
  for (int L = 0; L < 3; ++L){
    int in_dim = L ? HIDD : EMBD;
    float* vf = vfold + L * 1152;
    const u16* wt = (L == 0) ? wt0 : ((L == 1) ? wt1 : wt2);
    dim3 gg(OUTC / 128, (N_NODES + 63) / 64);
    if (L == 0) k_gemm<EMBD><<<gg, 256, 0, stream>>>(xbcur, wt, hbuf, N_NODES);
    else        k_gemm<HIDD><<<gg, 256, 0, stream>>>(xbcur, wt, hbuf, N_NODES);
    k_nodelin<<<(N_NODES + 255) / 256, 256, 0, stream>>>(xcur, vf,
        (const float4*)(proj + (size_t)L * N_NODES * 4), deg,
        s_src, s_dst, al_loop, in_dim);
    k_aggr<<<(N_NODES + 3) / 4, 256, 0, stream>>>((const uint4*)hbuf,
        (const float4*)(eaPc + (size_t)L * N_EDG * 4),
        (const float4*)s_src, (const float4*)s_dst, (const float4*)al_loop,
        rowptr, csr_src,
        bias + L * HIDD, lng + L * HIDD, lnb + L * HIDD, xout, xbout);
    xcur = xout; xbcur = xbout;
    xout = (L == 0) ? xB : xA;
    xbout = (L == 0) ? xbfB : xbfA;
  }

  k_pool<<<NB, 256, 0, stream>>>(xcur, bnd, (float*)d_out);
}